// Round 4
// baseline (632.699 us; speedup 1.0000x reference)
//
#include <hip/hip_runtime.h>
#include <hip/hip_bf16.h>

typedef __attribute__((ext_vector_type(8))) short bf16x8;
typedef __attribute__((ext_vector_type(4))) float f32x4;
typedef __attribute__((ext_vector_type(4))) unsigned short u16x4;
typedef unsigned short u16;
typedef unsigned int u32;

#define BSZ 16
#define RO 10752000
#define AO 11289600
#define SO 11306400

__device__ __forceinline__ float sigm(float x) { return 1.f / (1.f + __expf(-x)); }

__device__ __forceinline__ u16 f2bf(float f) {
  u32 u = __float_as_uint(f);
  u = u + 0x7FFF + ((u >> 16) & 1);
  return (u16)(u >> 16);
}
__device__ __forceinline__ float bf2f(u16 v) { return __uint_as_float(((u32)v) << 16); }

__device__ __forceinline__ void gll16(const void* g, void* l) {
  __builtin_amdgcn_global_load_lds((const __attribute__((address_space(1))) void*)g,
                                   (__attribute__((address_space(3))) void*)l, 16, 0, 0);
}

// ---------------- anchors ----------------
__global__ __launch_bounds__(256) void k_anchor(float* out) {
  int g = blockIdx.x * 256 + threadIdx.x;
  if (g >= 8400) return;
  int l = g < 400 ? 0 : (g < 2000 ? 1 : 2);
  int off = l == 0 ? 0 : (l == 1 ? 400 : 2000);
  int w = 20 << l;
  float s = (float)(32 >> l);
  int p = g - off;
  int x = p % w, y = p / w;
  out[AO + 2 * g] = x + 0.5f;
  out[AO + 2 * g + 1] = y + 0.5f;
  out[SO + g] = s;
}

// ---------------- avg pool ----------------
struct SmallArgs {
  const float* feat[3];
  const float *cfw[3], *cfb[3], *rfw[3], *rfb[3];
  float *avg, *gc, *gr;
};

__global__ __launch_bounds__(256) void k_avg(SmallArgs A, int s1, int s2) {
  int bid = blockIdx.x;
  int l = bid >= s2 ? 2 : (bid >= s1 ? 1 : 0);
  int loc = bid - (l == 2 ? s2 : (l == 1 ? s1 : 0));
  int C = 768 >> l, HW = 400 << (2 * l);
  int c = loc % C, b = loc / C;
  const float* src = A.feat[l] + (size_t)(b * C + c) * HW;
  float s = 0.f;
  for (int i = threadIdx.x; i < HW; i += 256) s += src[i];
  __shared__ float red[256];
  red[threadIdx.x] = s;
  __syncthreads();
  for (int o = 128; o > 0; o >>= 1) {
    if (threadIdx.x < o) red[threadIdx.x] += red[threadIdx.x + o];
    __syncthreads();
  }
  if (threadIdx.x == 0) A.avg[(l * BSZ + b) * 768 + c] = red[0] / (float)HW;
}

// ---------------- gates ----------------
__global__ __launch_bounds__(256) void k_gate(SmallArgs A, int s1, int s2) {
  int bid = blockIdx.x;
  int l = bid >= s2 ? 2 : (bid >= s1 ? 1 : 0);
  int loc = bid - (l == 2 ? s2 : (l == 1 ? s1 : 0));
  int C = 768 >> l;
  int co = loc % C, b = loc / C;
  const float* av = A.avg + (l * BSZ + b) * 768;
  float sc = 0.f, sr = 0.f;
  for (int ci = threadIdx.x; ci < C; ci += 256) {
    float v = av[ci];
    sc += A.cfw[l][(size_t)co * C + ci] * v;
    sr += A.rfw[l][(size_t)co * C + ci] * v;
  }
  __shared__ float rc[256], rr[256];
  rc[threadIdx.x] = sc; rr[threadIdx.x] = sr;
  __syncthreads();
  for (int o = 128; o > 0; o >>= 1) {
    if (threadIdx.x < o) { rc[threadIdx.x] += rc[threadIdx.x + o]; rr[threadIdx.x] += rr[threadIdx.x + o]; }
    __syncthreads();
  }
  if (threadIdx.x == 0) {
    A.gc[(l * BSZ + b) * 768 + co] = sigm(rc[0] + A.cfb[l][co]);
    A.gr[(l * BSZ + b) * 768 + co] = sigm(rr[0] + A.rfb[l][co]);
  }
}

// ---------------- featT prep: feat f32 [b][c][p] -> bf16 [b][p][c] ----------------
struct PFArgs { const float* feat[3]; u16* fT[3]; };

__global__ __launch_bounds__(128) void k_prepF(PFArgs A, int s1, int s2) {
  int bid = blockIdx.x;
  int l = bid >= s2 ? 2 : (bid >= s1 ? 1 : 0);
  int loc = bid - (l == 2 ? s2 : (l == 1 ? s1 : 0));
  int C = 768 >> l, HW = 400 << (2 * l);
  int PT = (HW + 127) / 128;
  int pt = loc % PT, b = loc / PT;
  int p = pt * 128 + threadIdx.x;
  bool ok = p < HW;
  int pp = ok ? p : HW - 1;
  const float* src = A.feat[l] + (size_t)b * C * HW + pp;
  u16* dst = A.fT[l] + ((size_t)b * HW + pp) * C;
  for (int c0 = 0; c0 < C; c0 += 8) {
    bf16x8 h;
#pragma unroll
    for (int j = 0; j < 8; j++) h[j] = (short)f2bf(src[(size_t)(c0 + j) * HW]);
    if (ok) *(bf16x8*)(dst + c0) = h;
  }
}

// ---------------- weight pre-transpose for conv3: wT[t][96][C] ----------------
__global__ __launch_bounds__(256) void k_wprep(const float* w, u16* dst, int C) {
  int id = blockIdx.x * 256 + threadIdx.x;
  int co = id / C, ci = id - co * C;
  const float* s = w + (size_t)id * 9;
#pragma unroll
  for (int t = 0; t < 9; t++) dst[((size_t)(t * 96 + co)) * C + ci] = f2bf(s[t]);
}

// ---------------- conv1 OLD (R2 fallback): dual-branch 1x1 MFMA GEMM ----------------
struct C1Lvl {
  const float *feat, *w0, *b0, *w1, *b1, *gc, *gr;
  u16 *tcT, *trT;
  int C, HW, ntiles, mblks, bstart;
};
struct C1Args { C1Lvl l[3]; };

__global__ __launch_bounds__(256) void k_conv1(C1Args A) {
  __shared__ char smem[32768];  // A0 8K | A1 8K | B 16K
  int bid = blockIdx.x;
  int li = (bid >= A.l[2].bstart) ? 2 : (bid >= A.l[1].bstart ? 1 : 0);
  const C1Lvl& L = A.l[li];
  int loc = bid - L.bstart;
  int mb = loc % L.mblks;
  int t2 = loc / L.mblks;
  int nt = t2 % L.ntiles;
  int b = t2 / L.ntiles;
  const int C = L.C, HW = L.HW;
  int p0 = nt * 128, co0 = mb * 64;
  int tid = threadIdx.x, lane = tid & 63, w = tid >> 6;
  int wm = w >> 1, wn = w & 1;
  char* A0 = smem;
  char* A1 = smem + 8192;
  char* Bb = smem + 16384;
  const float* gate0 = L.gc + b * 768;
  const float* gate1 = L.gr + b * 768;
  const float* feat_b = L.feat + (size_t)b * C * HW;
  int sk = tid >> 2, sq = tid & 3;

  f32x4 acc0[2][4], acc1[2][4];
#pragma unroll
  for (int mi = 0; mi < 2; mi++)
#pragma unroll
    for (int ni = 0; ni < 4; ni++) { acc0[mi][ni] = (f32x4){0.f,0.f,0.f,0.f}; acc1[mi][ni] = (f32x4){0.f,0.f,0.f,0.f}; }

  const int nchunk = C >> 6;
  for (int c = 0; c < nchunk; c++) {
    int ci0 = c << 6;
#pragma unroll
    for (int g = 0; g < 2; g++) {
      int u = g * 256 + tid;
      int m = u >> 3, s = u & 7;
      const float* wr0 = L.w0 + (size_t)(co0 + m) * C + ci0 + s * 8;
      const float* wr1 = L.w1 + (size_t)(co0 + m) * C + ci0 + s * 8;
      const float* g0 = gate0 + ci0 + s * 8;
      const float* g1 = gate1 + ci0 + s * 8;
      bf16x8 h0, h1;
#pragma unroll
      for (int j = 0; j < 8; j++) {
        h0[j] = (short)f2bf(wr0[j] * g0[j]);
        h1[j] = (short)f2bf(wr1[j] * g1[j]);
      }
      int off = m * 128 + ((s ^ (m & 7)) << 4);
      *(bf16x8*)(A0 + off) = h0;
      *(bf16x8*)(A1 + off) = h1;
    }
    {
      const float* sp = feat_b + (size_t)(ci0 + sk) * HW + p0 + sq * 32;
      if (p0 + 128 <= HW) {
#pragma unroll
        for (int j4 = 0; j4 < 8; j4++) {
          f32x4 v = *(const f32x4*)(sp + j4 * 4);
#pragma unroll
          for (int e = 0; e < 4; e++) {
            int n = sq * 32 + j4 * 4 + e;
            *(u16*)(Bb + n * 128 + (((sk >> 3) ^ (n & 7)) << 4) + ((sk & 7) << 1)) = f2bf(v[e]);
          }
        }
      } else {
#pragma unroll
        for (int j = 0; j < 32; j++) {
          int p = p0 + sq * 32 + j;
          float v = (p < HW) ? sp[j] : 0.f;
          int n = sq * 32 + j;
          *(u16*)(Bb + n * 128 + (((sk >> 3) ^ (n & 7)) << 4) + ((sk & 7) << 1)) = f2bf(v);
        }
      }
    }
    __syncthreads();
#pragma unroll
    for (int ks = 0; ks < 2; ks++) {
      int sl = ks * 4 + (lane >> 4);
      bf16x8 a0[2], a1[2], bfr[4];
#pragma unroll
      for (int mi = 0; mi < 2; mi++) {
        int row = wm * 32 + mi * 16 + (lane & 15);
        int off = row * 128 + ((sl ^ (row & 7)) << 4);
        a0[mi] = *(const bf16x8*)(A0 + off);
        a1[mi] = *(const bf16x8*)(A1 + off);
      }
#pragma unroll
      for (int ni = 0; ni < 4; ni++) {
        int row = wn * 64 + ni * 16 + (lane & 15);
        bfr[ni] = *(const bf16x8*)(Bb + row * 128 + ((sl ^ (row & 7)) << 4));
      }
#pragma unroll
      for (int mi = 0; mi < 2; mi++)
#pragma unroll
        for (int ni = 0; ni < 4; ni++) {
          acc0[mi][ni] = __builtin_amdgcn_mfma_f32_16x16x32_bf16(a0[mi], bfr[ni], acc0[mi][ni], 0, 0, 0);
          acc1[mi][ni] = __builtin_amdgcn_mfma_f32_16x16x32_bf16(a1[mi], bfr[ni], acc1[mi][ni], 0, 0, 0);
        }
    }
    __syncthreads();
  }
#pragma unroll
  for (int mi = 0; mi < 2; mi++) {
    int cob = co0 + wm * 32 + mi * 16 + ((lane >> 4) << 2);
    f32x4 bia0 = *(const f32x4*)(L.b0 + cob);
    f32x4 bia1 = *(const f32x4*)(L.b1 + cob);
#pragma unroll
    for (int ni = 0; ni < 4; ni++) {
      int n = wn * 64 + ni * 16 + (lane & 15);
      int p = p0 + n;
      if (p >= HW) continue;
      u16x4 o0, o1;
#pragma unroll
      for (int j = 0; j < 4; j++) {
        float x0 = acc0[mi][ni][j] + bia0[j];
        float r = feat_b[(size_t)(cob + j) * HW + p];
        o0[j] = f2bf(x0 * sigm(x0) + r);
        float x1 = acc1[mi][ni][j] + bia1[j];
        o1[j] = f2bf(x1 * sigm(x1));
      }
      size_t off = ((size_t)b * HW + p) * C + cob;
      *(u16x4*)(L.tcT + off) = o0;
      *(u16x4*)(L.trT + off) = o1;
    }
  }
}

// ---------------- conv1 NEW: B + residual from featT (gll staging) ----------------
struct C1NLvl {
  const float *w0, *b0, *w1, *b1, *gc, *gr;
  const u16* fT;
  u16 *tcT, *trT;
  int C, HW, ntiles, mblks, bstart;
};
struct C1NArgs { C1NLvl l[3]; const u16* zp; };

__global__ __launch_bounds__(256) void k_conv1n(C1NArgs A) {
  __shared__ char smem[32768];  // A0 8K | A1 8K | B 16K
  int bid = blockIdx.x;
  int li = (bid >= A.l[2].bstart) ? 2 : (bid >= A.l[1].bstart ? 1 : 0);
  const C1NLvl& L = A.l[li];
  int loc = bid - L.bstart;
  int mb = loc % L.mblks;
  int t2 = loc / L.mblks;
  int nt = t2 % L.ntiles;
  int b = t2 / L.ntiles;
  const int C = L.C, HW = L.HW;
  int p0 = nt * 128, co0 = mb * 64;
  int tid = threadIdx.x, lane = tid & 63, w = tid >> 6;
  int wm = w >> 1, wn = w & 1;
  char* A0 = smem;
  char* A1 = smem + 8192;
  char* Bb = smem + 16384;
  const float* gate0 = L.gc + b * 768;
  const float* gate1 = L.gr + b * 768;
  const u16* fTb = L.fT + (size_t)b * HW * C;
  int sl8 = lane & 7;

  const u16* bsrc[4];
  bool bval[4];
#pragma unroll
  for (int i = 0; i < 4; i++) {
    int r = w * 32 + i * 8 + (lane >> 3);
    int p = p0 + r;
    bval[i] = p < HW;
    bsrc[i] = bval[i] ? (fTb + (size_t)p * C + ((sl8 ^ (r & 7)) << 3)) : A.zp;
  }

  f32x4 acc0[2][4], acc1[2][4];
#pragma unroll
  for (int mi = 0; mi < 2; mi++)
#pragma unroll
    for (int ni = 0; ni < 4; ni++) { acc0[mi][ni] = (f32x4){0.f,0.f,0.f,0.f}; acc1[mi][ni] = (f32x4){0.f,0.f,0.f,0.f}; }

  const int nchunk = C >> 6;
  for (int c = 0; c < nchunk; c++) {
    int ci0 = c << 6;
    // B stage first (loads fly while A converts)
#pragma unroll
    for (int i = 0; i < 4; i++) {
      const void* src = bval[i] ? (const void*)(bsrc[i] + ci0) : (const void*)A.zp;
      gll16(src, Bb + (w * 32 + i * 8) * 128);
    }
    // A stage: gated weights, f32->bf16, vector swizzled stores
#pragma unroll
    for (int g = 0; g < 2; g++) {
      int u = g * 256 + tid;
      int m = u >> 3, s = u & 7;
      const float* wr0 = L.w0 + (size_t)(co0 + m) * C + ci0 + s * 8;
      const float* wr1 = L.w1 + (size_t)(co0 + m) * C + ci0 + s * 8;
      const float* g0 = gate0 + ci0 + s * 8;
      const float* g1 = gate1 + ci0 + s * 8;
      f32x4 wa0 = *(const f32x4*)(wr0), wb0 = *(const f32x4*)(wr0 + 4);
      f32x4 wa1 = *(const f32x4*)(wr1), wb1 = *(const f32x4*)(wr1 + 4);
      f32x4 ga = *(const f32x4*)(g0), gb = *(const f32x4*)(g0 + 4);
      f32x4 ra = *(const f32x4*)(g1), rb = *(const f32x4*)(g1 + 4);
      bf16x8 h0, h1;
#pragma unroll
      for (int j = 0; j < 4; j++) {
        h0[j] = (short)f2bf(wa0[j] * ga[j]);
        h0[j + 4] = (short)f2bf(wb0[j] * gb[j]);
        h1[j] = (short)f2bf(wa1[j] * ra[j]);
        h1[j + 4] = (short)f2bf(wb1[j] * rb[j]);
      }
      int off = m * 128 + ((s ^ (m & 7)) << 4);
      *(bf16x8*)(A0 + off) = h0;
      *(bf16x8*)(A1 + off) = h1;
    }
    __syncthreads();
#pragma unroll
    for (int ks = 0; ks < 2; ks++) {
      int sl = ks * 4 + (lane >> 4);
      bf16x8 a0[2], a1[2], bfr[4];
#pragma unroll
      for (int mi = 0; mi < 2; mi++) {
        int row = wm * 32 + mi * 16 + (lane & 15);
        int off = row * 128 + ((sl ^ (row & 7)) << 4);
        a0[mi] = *(const bf16x8*)(A0 + off);
        a1[mi] = *(const bf16x8*)(A1 + off);
      }
#pragma unroll
      for (int ni = 0; ni < 4; ni++) {
        int row = wn * 64 + ni * 16 + (lane & 15);
        bfr[ni] = *(const bf16x8*)(Bb + row * 128 + ((sl ^ (row & 7)) << 4));
      }
#pragma unroll
      for (int mi = 0; mi < 2; mi++)
#pragma unroll
        for (int ni = 0; ni < 4; ni++) {
          acc0[mi][ni] = __builtin_amdgcn_mfma_f32_16x16x32_bf16(a0[mi], bfr[ni], acc0[mi][ni], 0, 0, 0);
          acc1[mi][ni] = __builtin_amdgcn_mfma_f32_16x16x32_bf16(a1[mi], bfr[ni], acc1[mi][ni], 0, 0, 0);
        }
    }
    __syncthreads();
  }
  // epilogue: silu(+bias); cls adds residual (from featT); store bf16 [b][p][C]
#pragma unroll
  for (int mi = 0; mi < 2; mi++) {
    int cob = co0 + wm * 32 + mi * 16 + ((lane >> 4) << 2);
    f32x4 bia0 = *(const f32x4*)(L.b0 + cob);
    f32x4 bia1 = *(const f32x4*)(L.b1 + cob);
#pragma unroll
    for (int ni = 0; ni < 4; ni++) {
      int n = wn * 64 + ni * 16 + (lane & 15);
      int p = p0 + n;
      if (p >= HW) continue;
      u16x4 res = *(const u16x4*)(fTb + (size_t)p * C + cob);
      u16x4 o0, o1;
#pragma unroll
      for (int j = 0; j < 4; j++) {
        float x0 = acc0[mi][ni][j] + bia0[j];
        o0[j] = f2bf(x0 * sigm(x0) + bf2f(res[j]));
        float x1 = acc1[mi][ni][j] + bia1[j];
        o1[j] = f2bf(x1 * sigm(x1));
      }
      size_t off = ((size_t)b * HW + p) * C + cob;
      *(u16x4*)(L.tcT + off) = o0;
      *(u16x4*)(L.trT + off) = o1;
    }
  }
}

// ---------------- conv3: 3x3 MFMA implicit GEMM (tap-outer), M=96 N=128 K=C per tap ----------------
struct C3Lvl {
  const u16* inT;
  const float* w;
  const u16* wT;
  const float* bias;
  int C, W, H, HW, ntiles, bstart, pos_off;
};
struct C3Args { C3Lvl l[3]; const u16* zp; float* out; };

template<int MREAL, int EPI, bool WT>
__global__ __launch_bounds__(256) void k_conv3(C3Args A) {
  __shared__ char smem[EPI == 3 ? 34816 : 28672];  // A 12K | B 16K
  char* Ab = smem;
  char* Bb = smem + 12288;
  int bid = blockIdx.x;
  int li = (bid >= A.l[2].bstart) ? 2 : (bid >= A.l[1].bstart ? 1 : 0);
  const C3Lvl& L = A.l[li];
  int loc = bid - L.bstart;
  int nt = loc % L.ntiles;
  int b = loc / L.ntiles;
  const int C = L.C, W = L.W, H = L.H, HW = L.HW;
  int p0 = nt * 128;
  int tid = threadIdx.x, lane = tid & 63, w = tid >> 6;
  int wm = w >> 1, wn = w & 1;
  int sl8 = lane & 7;
  const u16* inb = L.inT + (size_t)b * HW * C;

  int rr[4], px[4], py[4];
  bool pv[4];
#pragma unroll
  for (int i = 0; i < 4; i++) {
    int r = w * 32 + i * 8 + (lane >> 3);
    rr[i] = r;
    int p = p0 + r;
    pv[i] = p < HW;
    int pp = pv[i] ? p : 0;
    px[i] = pp % W;
    py[i] = pp / W;
  }

  f32x4 acc[3][4];
#pragma unroll
  for (int mi = 0; mi < 3; mi++)
#pragma unroll
    for (int ni = 0; ni < 4; ni++) acc[mi][ni] = (f32x4){0.f,0.f,0.f,0.f};

  const int nchunk = C >> 6;
  for (int t = 0; t < 9; t++) {
    int dy = t / 3 - 1, dx = t - (t / 3) * 3 - 1;
    const u16* bs[4];
    bool bv[4];
#pragma unroll
    for (int i = 0; i < 4; i++) {
      int xx = px[i] + dx, yy = py[i] + dy;
      bool ok = pv[i] && ((unsigned)xx < (unsigned)W) && ((unsigned)yy < (unsigned)H);
      bv[i] = ok;
      int q = p0 + rr[i] + dy * W + dx;
      bs[i] = ok ? (inb + (size_t)q * C + ((sl8 ^ (rr[i] & 7)) << 3)) : A.zp;
    }
    for (int c = 0; c < nchunk; c++) {
      int ci0 = c << 6;
      if (WT) {
        const u16* wl = L.wT;
#pragma unroll
        for (int g = 0; g < 3; g++) {
          int row = w * 24 + g * 8 + (lane >> 3);
          const u16* src = wl + ((size_t)(t * 96 + row)) * C + ci0 + ((sl8 ^ (row & 7)) << 3);
          gll16(src, Ab + (w * 24 + g * 8) * 128);
        }
      } else {
#pragma unroll
        for (int g = 0; g < 3; g++) {
          int u = g * 256 + tid;
          int am = u >> 3, as = u & 7;
          bf16x8 h;
          if (am < MREAL) {
            const float* wp = L.w + ((size_t)am * C + ci0 + as * 8) * 9 + t;
#pragma unroll
            for (int j = 0; j < 8; j++) h[j] = (short)f2bf(wp[j * 9]);
          } else {
#pragma unroll
            for (int j = 0; j < 8; j++) h[j] = 0;
          }
          *(bf16x8*)(Ab + am * 128 + ((as ^ (am & 7)) << 4)) = h;
        }
      }
#pragma unroll
      for (int i = 0; i < 4; i++) {
        const void* src = bv[i] ? (const void*)(bs[i] + ci0) : (const void*)A.zp;
        gll16(src, Bb + (w * 32 + i * 8) * 128);
      }
      __syncthreads();
#pragma unroll
      for (int ks = 0; ks < 2; ks++) {
        int sl = ks * 4 + (lane >> 4);
        bf16x8 af[3], bfr[4];
#pragma unroll
        for (int mi = 0; mi < 3; mi++) {
          int row = wm * 48 + mi * 16 + (lane & 15);
          af[mi] = *(const bf16x8*)(Ab + row * 128 + ((sl ^ (row & 7)) << 4));
        }
#pragma unroll
        for (int ni = 0; ni < 4; ni++) {
          int row = wn * 64 + ni * 16 + (lane & 15);
          bfr[ni] = *(const bf16x8*)(Bb + row * 128 + ((sl ^ (row & 7)) << 4));
        }
#pragma unroll
        for (int mi = 0; mi < 3; mi++)
#pragma unroll
          for (int ni = 0; ni < 4; ni++)
            acc[mi][ni] = __builtin_amdgcn_mfma_f32_16x16x32_bf16(af[mi], bfr[ni], acc[mi][ni], 0, 0, 0);
      }
      __syncthreads();
    }
  }

  if (EPI == 2) {
#pragma unroll
    for (int mi = 0; mi < 3; mi++) {
      int cob = wm * 48 + mi * 16 + ((lane >> 4) << 2);
      if (cob >= 80) continue;
      f32x4 bia = *(const f32x4*)(L.bias + cob);
#pragma unroll
      for (int ni = 0; ni < 4; ni++) {
        int n = wn * 64 + ni * 16 + (lane & 15);
        int p = p0 + n;
        if (p >= HW) continue;
#pragma unroll
        for (int j = 0; j < 4; j++) {
          A.out[(size_t)(b * 80 + cob + j) * 8400 + L.pos_off + p] = sigm(acc[mi][ni][j] + bia[j]);
        }
      }
    }
  } else {
    float* P = (float*)smem;  // [128][68]
#pragma unroll
    for (int mi = 0; mi < 3; mi++) {
      int cob = wm * 48 + mi * 16 + ((lane >> 4) << 2);
      if (cob < 68) {
        f32x4 bia = *(const f32x4*)(L.bias + cob);
#pragma unroll
        for (int ni = 0; ni < 4; ni++) {
          int n = wn * 64 + ni * 16 + (lane & 15);
          f32x4 v = acc[mi][ni];
#pragma unroll
          for (int j = 0; j < 4; j++) v[j] += bia[j];
          *(f32x4*)(P + n * 68 + cob) = v;
        }
      }
    }
    __syncthreads();
    int n = tid >> 1, g2 = tid & 1;
    int p = p0 + n;
    if (p < HW) {
      float d[2];
#pragma unroll
      for (int gg = 0; gg < 2; gg++) {
        const float* row = P + n * 68 + (g2 * 2 + gg) * 17;
        float mx = row[0];
#pragma unroll
        for (int k = 1; k < 17; k++) mx = fmaxf(mx, row[k]);
        float sum = 0.f, dot = 0.f;
#pragma unroll
        for (int k = 0; k < 17; k++) {
          float e = __expf(row[k] - mx);
          sum += e;
          dot += (float)k * e;
        }
        d[gg] = dot / sum;
      }
      float2 dv = make_float2(d[0], d[1]);
      *(float2*)(A.out + RO + ((size_t)b * 8400 + L.pos_off + p) * 4 + g2 * 2) = dv;
    }
  }
}

// ---------------- host ----------------
extern "C" void kernel_launch(void* const* d_in, const int* in_sizes, int n_in,
                              void* d_out, int out_size, void* d_ws, size_t ws_size,
                              hipStream_t stream) {
  static const int Cs[3] = {768, 384, 192};
  static const int HWs[3] = {400, 1600, 6400};
  static const int Ws[3] = {20, 40, 80};
  static const int POs[3] = {0, 400, 2000};
  static const long TOFF[3] = {0, 4915200, 14745600};
  static const long WTOFF[3] = {0, 663552, 995328};
  static const int NT[3] = {4, 13, 50};
  static const int MB[3] = {12, 6, 3};

  char* wsb = (char*)d_ws;
  u16* zp = (u16*)wsb;
  float* avg = (float*)(wsb + 256);
  float* gc = avg + 3 * BSZ * 768;
  float* gr = gc + 3 * BSZ * 768;
  u16* tcT = (u16*)(gr + 3 * BSZ * 768);
  u16* trT = tcT + 34406400;
  u16* wTc = trT + 34406400;
  u16* wTr = wTc + 1161216;
  u16* featT = wTr + 1161216;
  const size_t NEED_WT = 142713088ull;   // through wTr
  const size_t NEED_NEW = 211525888ull;  // + featT
  bool useWT = ws_size >= NEED_WT;
  bool useNEW = ws_size >= NEED_NEW;

  hipMemsetAsync(zp, 0, 256, stream);

  SmallArgs SA;
  for (int l = 0; l < 3; l++) {
    const float* const* p = (const float* const*)(d_in + l * 13);
    SA.feat[l] = p[0];
    SA.cfw[l] = p[1]; SA.cfb[l] = p[2];
    SA.rfw[l] = p[3]; SA.rfb[l] = p[4];
  }
  SA.avg = avg; SA.gc = gc; SA.gr = gr;

  if (useWT) {
    hipMemsetAsync(wTc, 0, 2 * 1161216ull * 2, stream);
    for (int l = 0; l < 3; l++) {
      const float* pcw = (const float*)d_in[l * 13 + 9];
      const float* prw = (const float*)d_in[l * 13 + 11];
      hipLaunchKernelGGL(k_wprep, dim3(80 * Cs[l] / 256), dim3(256), 0, stream, pcw, wTc + WTOFF[l], Cs[l]);
      hipLaunchKernelGGL(k_wprep, dim3(68 * Cs[l] / 256), dim3(256), 0, stream, prw, wTr + WTOFF[l], Cs[l]);
    }
  }

  if (useNEW) {
    PFArgs PF;
    for (int l = 0; l < 3; l++) {
      PF.feat[l] = SA.feat[l];
      PF.fT[l] = featT + TOFF[l];
    }
    int ps1 = BSZ * 4, ps2 = ps1 + BSZ * 13, ptot = ps2 + BSZ * 50;
    hipLaunchKernelGGL(k_prepF, dim3(ptot), dim3(128), 0, stream, PF, ps1, ps2);
  }

  int s1 = BSZ * 768, s2 = s1 + BSZ * 384, tot = s2 + BSZ * 192;
  hipLaunchKernelGGL(k_avg, dim3(tot), dim3(256), 0, stream, SA, s1, s2);
  hipLaunchKernelGGL(k_gate, dim3(tot), dim3(256), 0, stream, SA, s1, s2);

  int bstart = 0;
  if (useNEW) {
    C1NArgs C1;
    for (int l = 0; l < 3; l++) {
      const float* const* p = (const float* const*)(d_in + l * 13);
      C1NLvl& L = C1.l[l];
      L.w0 = p[5]; L.b0 = p[6];
      L.w1 = p[7]; L.b1 = p[8];
      L.gc = gc + l * BSZ * 768;
      L.gr = gr + l * BSZ * 768;
      L.fT = featT + TOFF[l];
      L.tcT = tcT + TOFF[l];
      L.trT = trT + TOFF[l];
      L.C = Cs[l]; L.HW = HWs[l]; L.ntiles = NT[l]; L.mblks = MB[l];
      L.bstart = bstart;
      bstart += BSZ * NT[l] * MB[l];
    }
    C1.zp = zp;
    hipLaunchKernelGGL(k_conv1n, dim3(bstart), dim3(256), 0, stream, C1);
  } else {
    C1Args C1;
    for (int l = 0; l < 3; l++) {
      const float* const* p = (const float* const*)(d_in + l * 13);
      C1Lvl& L = C1.l[l];
      L.feat = p[0];
      L.w0 = p[5]; L.b0 = p[6];
      L.w1 = p[7]; L.b1 = p[8];
      L.gc = gc + l * BSZ * 768;
      L.gr = gr + l * BSZ * 768;
      L.tcT = tcT + TOFF[l];
      L.trT = trT + TOFF[l];
      L.C = Cs[l]; L.HW = HWs[l]; L.ntiles = NT[l]; L.mblks = MB[l];
      L.bstart = bstart;
      bstart += BSZ * NT[l] * MB[l];
    }
    hipLaunchKernelGGL(k_conv1, dim3(bstart), dim3(256), 0, stream, C1);
  }

  C3Args C3c, C3r;
  int bs3 = 0;
  for (int l = 0; l < 3; l++) {
    const float* const* p = (const float* const*)(d_in + l * 13);
    C3Lvl Lc, Lr;
    Lc.inT = tcT + TOFF[l]; Lc.w = p[9]; Lc.wT = wTc + WTOFF[l]; Lc.bias = p[10];
    Lr.inT = trT + TOFF[l]; Lr.w = p[11]; Lr.wT = wTr + WTOFF[l]; Lr.bias = p[12];
    Lc.C = Lr.C = Cs[l]; Lc.W = Lr.W = Ws[l]; Lc.H = Lr.H = Ws[l]; Lc.HW = Lr.HW = HWs[l];
    Lc.ntiles = Lr.ntiles = NT[l];
    Lc.bstart = Lr.bstart = bs3;
    Lc.pos_off = Lr.pos_off = POs[l];
    C3c.l[l] = Lc; C3r.l[l] = Lr;
    bs3 += BSZ * NT[l];
  }
  C3c.zp = zp; C3c.out = (float*)d_out;
  C3r.zp = zp; C3r.out = (float*)d_out;

  if (useWT) {
    hipLaunchKernelGGL((k_conv3<80, 2, true>), dim3(bs3), dim3(256), 0, stream, C3c);
    hipLaunchKernelGGL((k_conv3<68, 3, true>), dim3(bs3), dim3(256), 0, stream, C3r);
  } else {
    hipLaunchKernelGGL((k_conv3<80, 2, false>), dim3(bs3), dim3(256), 0, stream, C3c);
    hipLaunchKernelGGL((k_conv3<68, 3, false>), dim3(bs3), dim3(256), 0, stream, C3r);
  }

  hipLaunchKernelGGL(k_anchor, dim3(33), dim3(256), 0, stream, (float*)d_out);
}

// Round 5
// 566.750 us; speedup vs baseline: 1.1164x; 1.1164x over previous
//
#include <hip/hip_runtime.h>
#include <hip/hip_bf16.h>

typedef __attribute__((ext_vector_type(8))) short bf16x8;
typedef __attribute__((ext_vector_type(4))) float f32x4;
typedef __attribute__((ext_vector_type(4))) unsigned short u16x4;
typedef unsigned short u16;
typedef unsigned int u32;

#define BSZ 16
#define RO 10752000
#define AO 11289600
#define SO 11306400

__device__ __forceinline__ float sigm(float x) { return 1.f / (1.f + __expf(-x)); }

__device__ __forceinline__ u16 f2bf(float f) {
  u32 u = __float_as_uint(f);
  u = u + 0x7FFF + ((u >> 16) & 1);
  return (u16)(u >> 16);
}
__device__ __forceinline__ float bf2f(u16 v) { return __uint_as_float(((u32)v) << 16); }

__device__ __forceinline__ void gll16(const void* g, void* l) {
  __builtin_amdgcn_global_load_lds((const __attribute__((address_space(1))) void*)g,
                                   (__attribute__((address_space(3))) void*)l, 16, 0, 0);
}

// ---------------- anchors ----------------
__global__ __launch_bounds__(256) void k_anchor(float* out) {
  int g = blockIdx.x * 256 + threadIdx.x;
  if (g >= 8400) return;
  int l = g < 400 ? 0 : (g < 2000 ? 1 : 2);
  int off = l == 0 ? 0 : (l == 1 ? 400 : 2000);
  int w = 20 << l;
  float s = (float)(32 >> l);
  int p = g - off;
  int x = p % w, y = p / w;
  out[AO + 2 * g] = x + 0.5f;
  out[AO + 2 * g + 1] = y + 0.5f;
  out[SO + g] = s;
}

// ---------------- avg pool ----------------
struct SmallArgs {
  const float* feat[3];
  const float *cfw[3], *cfb[3], *rfw[3], *rfb[3];
  float *avg, *gc, *gr;
};

__global__ __launch_bounds__(256) void k_avg(SmallArgs A, int s1, int s2) {
  int bid = blockIdx.x;
  int l = bid >= s2 ? 2 : (bid >= s1 ? 1 : 0);
  int loc = bid - (l == 2 ? s2 : (l == 1 ? s1 : 0));
  int C = 768 >> l, HW = 400 << (2 * l);
  int c = loc % C, b = loc / C;
  const float* src = A.feat[l] + (size_t)(b * C + c) * HW;
  float s = 0.f;
  for (int i = threadIdx.x; i < HW; i += 256) s += src[i];
  __shared__ float red[256];
  red[threadIdx.x] = s;
  __syncthreads();
  for (int o = 128; o > 0; o >>= 1) {
    if (threadIdx.x < o) red[threadIdx.x] += red[threadIdx.x + o];
    __syncthreads();
  }
  if (threadIdx.x == 0) A.avg[(l * BSZ + b) * 768 + c] = red[0] / (float)HW;
}

// ---------------- gates ----------------
__global__ __launch_bounds__(256) void k_gate(SmallArgs A, int s1, int s2) {
  int bid = blockIdx.x;
  int l = bid >= s2 ? 2 : (bid >= s1 ? 1 : 0);
  int loc = bid - (l == 2 ? s2 : (l == 1 ? s1 : 0));
  int C = 768 >> l;
  int co = loc % C, b = loc / C;
  const float* av = A.avg + (l * BSZ + b) * 768;
  float sc = 0.f, sr = 0.f;
  for (int ci = threadIdx.x; ci < C; ci += 256) {
    float v = av[ci];
    sc += A.cfw[l][(size_t)co * C + ci] * v;
    sr += A.rfw[l][(size_t)co * C + ci] * v;
  }
  __shared__ float rc[256], rr[256];
  rc[threadIdx.x] = sc; rr[threadIdx.x] = sr;
  __syncthreads();
  for (int o = 128; o > 0; o >>= 1) {
    if (threadIdx.x < o) { rc[threadIdx.x] += rc[threadIdx.x + o]; rr[threadIdx.x] += rr[threadIdx.x + o]; }
    __syncthreads();
  }
  if (threadIdx.x == 0) {
    A.gc[(l * BSZ + b) * 768 + co] = sigm(rc[0] + A.cfb[l][co]);
    A.gr[(l * BSZ + b) * 768 + co] = sigm(rr[0] + A.rfb[l][co]);
  }
}

// ---------------- featT prep v2: LDS-tiled transpose, coalesced both sides ----------------
struct PFArgs { const float* feat[3]; u16* fT[3]; };

__global__ __launch_bounds__(256) void k_prepF2(PFArgs A, int s1, int s2) {
  __shared__ float buf[32][65];
  int bid = blockIdx.x;
  int l = bid >= s2 ? 2 : (bid >= s1 ? 1 : 0);
  int loc = bid - (l == 2 ? s2 : (l == 1 ? s1 : 0));
  int C = 768 >> l, HW = 400 << (2 * l);
  int PT = (HW + 63) / 64;
  int pt = loc % PT, b = loc / PT;
  int p0 = pt * 64;
  int tid = threadIdx.x;
  int cc = tid >> 6, pp = tid & 63;
  int pload = p0 + pp;
  bool lok = pload < HW;
  int plc = lok ? pload : 0;
  int pw = tid >> 2, cg = (tid & 3) * 8;
  bool wok = p0 + pw < HW;
  const float* src = A.feat[l] + (size_t)b * C * HW;
  u16* dst = A.fT[l] + (size_t)b * HW * C;
  for (int c0 = 0; c0 < C; c0 += 32) {
#pragma unroll
    for (int j = 0; j < 8; j++) {
      int c = c0 + cc * 8 + j;
      buf[cc * 8 + j][pp] = src[(size_t)c * HW + plc];
    }
    __syncthreads();
    if (wok) {
      bf16x8 h;
#pragma unroll
      for (int j = 0; j < 8; j++) h[j] = (short)f2bf(buf[cg + j][pw]);
      *(bf16x8*)(dst + (size_t)(p0 + pw) * C + c0 + cg) = h;
    }
    __syncthreads();
  }
}

// ---------------- gated-weight prep: gw[b][co][ci] = bf16(w[co][ci] * g[b][ci]) ----------------
struct GWArgs {
  const float *w0[3], *w1[3];
  const float *gc, *gr;
  u16 *gwc, *gwr;
  long goff[3];
};

__global__ __launch_bounds__(256) void k_wgate(GWArgs A, int s1, int s2) {
  int bid = blockIdx.x;
  int l = bid >= s2 ? 2 : (bid >= s1 ? 1 : 0);
  int loc = bid - (l == 2 ? s2 : (l == 1 ? s1 : 0));
  int C = 768 >> l;
  int per_b = (C * C) >> 11;   // blocks per batch (2048 elems/block)
  int tile = loc % per_b, b = loc / per_b;
  int idx = (tile << 11) + threadIdx.x * 8;
  int co = idx / C, ci = idx - co * C;
  const float* g0 = A.gc + (l * BSZ + b) * 768 + ci;
  const float* g1 = A.gr + (l * BSZ + b) * 768 + ci;
  const float* w0 = A.w0[l] + idx;
  const float* w1 = A.w1[l] + idx;
  f32x4 wa0 = *(const f32x4*)(w0), wb0 = *(const f32x4*)(w0 + 4);
  f32x4 wa1 = *(const f32x4*)(w1), wb1 = *(const f32x4*)(w1 + 4);
  f32x4 ga = *(const f32x4*)(g0), gb = *(const f32x4*)(g0 + 4);
  f32x4 ra = *(const f32x4*)(g1), rb = *(const f32x4*)(g1 + 4);
  bf16x8 h0, h1;
#pragma unroll
  for (int j = 0; j < 4; j++) {
    h0[j] = (short)f2bf(wa0[j] * ga[j]);
    h0[j + 4] = (short)f2bf(wb0[j] * gb[j]);
    h1[j] = (short)f2bf(wa1[j] * ra[j]);
    h1[j + 4] = (short)f2bf(wb1[j] * rb[j]);
  }
  size_t o = A.goff[l] + (size_t)b * C * C + idx;
  *(bf16x8*)(A.gwc + o) = h0;
  *(bf16x8*)(A.gwr + o) = h1;
}

// ---------------- weight pre-transpose for conv3: wT[t][96][C] ----------------
__global__ __launch_bounds__(256) void k_wprep(const float* w, u16* dst, int C) {
  int id = blockIdx.x * 256 + threadIdx.x;
  int co = id / C, ci = id - co * C;
  const float* s = w + (size_t)id * 9;
#pragma unroll
  for (int t = 0; t < 9; t++) dst[((size_t)(t * 96 + co)) * C + ci] = f2bf(s[t]);
}

// ---------------- conv1 OLD (R2 fallback) ----------------
struct C1Lvl {
  const float *feat, *w0, *b0, *w1, *b1, *gc, *gr;
  u16 *tcT, *trT;
  int C, HW, ntiles, mblks, bstart;
};
struct C1Args { C1Lvl l[3]; };

__global__ __launch_bounds__(256) void k_conv1(C1Args A) {
  __shared__ char smem[32768];
  int bid = blockIdx.x;
  int li = (bid >= A.l[2].bstart) ? 2 : (bid >= A.l[1].bstart ? 1 : 0);
  const C1Lvl& L = A.l[li];
  int loc = bid - L.bstart;
  int mb = loc % L.mblks;
  int t2 = loc / L.mblks;
  int nt = t2 % L.ntiles;
  int b = t2 / L.ntiles;
  const int C = L.C, HW = L.HW;
  int p0 = nt * 128, co0 = mb * 64;
  int tid = threadIdx.x, lane = tid & 63, w = tid >> 6;
  int wm = w >> 1, wn = w & 1;
  char* A0 = smem;
  char* A1 = smem + 8192;
  char* Bb = smem + 16384;
  const float* gate0 = L.gc + b * 768;
  const float* gate1 = L.gr + b * 768;
  const float* feat_b = L.feat + (size_t)b * C * HW;
  int sk = tid >> 2, sq = tid & 3;

  f32x4 acc0[2][4], acc1[2][4];
#pragma unroll
  for (int mi = 0; mi < 2; mi++)
#pragma unroll
    for (int ni = 0; ni < 4; ni++) { acc0[mi][ni] = (f32x4){0.f,0.f,0.f,0.f}; acc1[mi][ni] = (f32x4){0.f,0.f,0.f,0.f}; }

  const int nchunk = C >> 6;
  for (int c = 0; c < nchunk; c++) {
    int ci0 = c << 6;
#pragma unroll
    for (int g = 0; g < 2; g++) {
      int u = g * 256 + tid;
      int m = u >> 3, s = u & 7;
      const float* wr0 = L.w0 + (size_t)(co0 + m) * C + ci0 + s * 8;
      const float* wr1 = L.w1 + (size_t)(co0 + m) * C + ci0 + s * 8;
      const float* g0 = gate0 + ci0 + s * 8;
      const float* g1 = gate1 + ci0 + s * 8;
      bf16x8 h0, h1;
#pragma unroll
      for (int j = 0; j < 8; j++) {
        h0[j] = (short)f2bf(wr0[j] * g0[j]);
        h1[j] = (short)f2bf(wr1[j] * g1[j]);
      }
      int off = m * 128 + ((s ^ (m & 7)) << 4);
      *(bf16x8*)(A0 + off) = h0;
      *(bf16x8*)(A1 + off) = h1;
    }
    {
      const float* sp = feat_b + (size_t)(ci0 + sk) * HW + p0 + sq * 32;
      if (p0 + 128 <= HW) {
#pragma unroll
        for (int j4 = 0; j4 < 8; j4++) {
          f32x4 v = *(const f32x4*)(sp + j4 * 4);
#pragma unroll
          for (int e = 0; e < 4; e++) {
            int n = sq * 32 + j4 * 4 + e;
            *(u16*)(Bb + n * 128 + (((sk >> 3) ^ (n & 7)) << 4) + ((sk & 7) << 1)) = f2bf(v[e]);
          }
        }
      } else {
#pragma unroll
        for (int j = 0; j < 32; j++) {
          int p = p0 + sq * 32 + j;
          float v = (p < HW) ? sp[j] : 0.f;
          int n = sq * 32 + j;
          *(u16*)(Bb + n * 128 + (((sk >> 3) ^ (n & 7)) << 4) + ((sk & 7) << 1)) = f2bf(v);
        }
      }
    }
    __syncthreads();
#pragma unroll
    for (int ks = 0; ks < 2; ks++) {
      int sl = ks * 4 + (lane >> 4);
      bf16x8 a0[2], a1[2], bfr[4];
#pragma unroll
      for (int mi = 0; mi < 2; mi++) {
        int row = wm * 32 + mi * 16 + (lane & 15);
        int off = row * 128 + ((sl ^ (row & 7)) << 4);
        a0[mi] = *(const bf16x8*)(A0 + off);
        a1[mi] = *(const bf16x8*)(A1 + off);
      }
#pragma unroll
      for (int ni = 0; ni < 4; ni++) {
        int row = wn * 64 + ni * 16 + (lane & 15);
        bfr[ni] = *(const bf16x8*)(Bb + row * 128 + ((sl ^ (row & 7)) << 4));
      }
#pragma unroll
      for (int mi = 0; mi < 2; mi++)
#pragma unroll
        for (int ni = 0; ni < 4; ni++) {
          acc0[mi][ni] = __builtin_amdgcn_mfma_f32_16x16x32_bf16(a0[mi], bfr[ni], acc0[mi][ni], 0, 0, 0);
          acc1[mi][ni] = __builtin_amdgcn_mfma_f32_16x16x32_bf16(a1[mi], bfr[ni], acc1[mi][ni], 0, 0, 0);
        }
    }
    __syncthreads();
  }
#pragma unroll
  for (int mi = 0; mi < 2; mi++) {
    int cob = co0 + wm * 32 + mi * 16 + ((lane >> 4) << 2);
    f32x4 bia0 = *(const f32x4*)(L.b0 + cob);
    f32x4 bia1 = *(const f32x4*)(L.b1 + cob);
#pragma unroll
    for (int ni = 0; ni < 4; ni++) {
      int n = wn * 64 + ni * 16 + (lane & 15);
      int p = p0 + n;
      if (p >= HW) continue;
      u16x4 o0, o1;
#pragma unroll
      for (int j = 0; j < 4; j++) {
        float x0 = acc0[mi][ni][j] + bia0[j];
        float r = feat_b[(size_t)(cob + j) * HW + p];
        o0[j] = f2bf(x0 * sigm(x0) + r);
        float x1 = acc1[mi][ni][j] + bia1[j];
        o1[j] = f2bf(x1 * sigm(x1));
      }
      size_t off = ((size_t)b * HW + p) * C + cob;
      *(u16x4*)(L.tcT + off) = o0;
      *(u16x4*)(L.trT + off) = o1;
    }
  }
}

// ---------------- conv1n (R3 fallback): featT B, in-loop gated A ----------------
struct C1NLvl {
  const float *w0, *b0, *w1, *b1, *gc, *gr;
  const u16* fT;
  u16 *tcT, *trT;
  int C, HW, ntiles, mblks, bstart;
};
struct C1NArgs { C1NLvl l[3]; const u16* zp; };

__global__ __launch_bounds__(256) void k_conv1n(C1NArgs A) {
  __shared__ char smem[32768];
  int bid = blockIdx.x;
  int li = (bid >= A.l[2].bstart) ? 2 : (bid >= A.l[1].bstart ? 1 : 0);
  const C1NLvl& L = A.l[li];
  int loc = bid - L.bstart;
  int mb = loc % L.mblks;
  int t2 = loc / L.mblks;
  int nt = t2 % L.ntiles;
  int b = t2 / L.ntiles;
  const int C = L.C, HW = L.HW;
  int p0 = nt * 128, co0 = mb * 64;
  int tid = threadIdx.x, lane = tid & 63, w = tid >> 6;
  int wm = w >> 1, wn = w & 1;
  char* A0 = smem;
  char* A1 = smem + 8192;
  char* Bb = smem + 16384;
  const float* gate0 = L.gc + b * 768;
  const float* gate1 = L.gr + b * 768;
  const u16* fTb = L.fT + (size_t)b * HW * C;
  int sl8 = lane & 7;

  const u16* bsrc[4];
  bool bval[4];
#pragma unroll
  for (int i = 0; i < 4; i++) {
    int r = w * 32 + i * 8 + (lane >> 3);
    int p = p0 + r;
    bval[i] = p < HW;
    bsrc[i] = bval[i] ? (fTb + (size_t)p * C + ((sl8 ^ (r & 7)) << 3)) : A.zp;
  }

  f32x4 acc0[2][4], acc1[2][4];
#pragma unroll
  for (int mi = 0; mi < 2; mi++)
#pragma unroll
    for (int ni = 0; ni < 4; ni++) { acc0[mi][ni] = (f32x4){0.f,0.f,0.f,0.f}; acc1[mi][ni] = (f32x4){0.f,0.f,0.f,0.f}; }

  const int nchunk = C >> 6;
  for (int c = 0; c < nchunk; c++) {
    int ci0 = c << 6;
#pragma unroll
    for (int i = 0; i < 4; i++) {
      const void* src = bval[i] ? (const void*)(bsrc[i] + ci0) : (const void*)A.zp;
      gll16(src, Bb + (w * 32 + i * 8) * 128);
    }
#pragma unroll
    for (int g = 0; g < 2; g++) {
      int u = g * 256 + tid;
      int m = u >> 3, s = u & 7;
      const float* wr0 = L.w0 + (size_t)(co0 + m) * C + ci0 + s * 8;
      const float* wr1 = L.w1 + (size_t)(co0 + m) * C + ci0 + s * 8;
      const float* g0 = gate0 + ci0 + s * 8;
      const float* g1 = gate1 + ci0 + s * 8;
      f32x4 wa0 = *(const f32x4*)(wr0), wb0 = *(const f32x4*)(wr0 + 4);
      f32x4 wa1 = *(const f32x4*)(wr1), wb1 = *(const f32x4*)(wr1 + 4);
      f32x4 ga = *(const f32x4*)(g0), gb = *(const f32x4*)(g0 + 4);
      f32x4 ra = *(const f32x4*)(g1), rb = *(const f32x4*)(g1 + 4);
      bf16x8 h0, h1;
#pragma unroll
      for (int j = 0; j < 4; j++) {
        h0[j] = (short)f2bf(wa0[j] * ga[j]);
        h0[j + 4] = (short)f2bf(wb0[j] * gb[j]);
        h1[j] = (short)f2bf(wa1[j] * ra[j]);
        h1[j + 4] = (short)f2bf(wb1[j] * rb[j]);
      }
      int off = m * 128 + ((s ^ (m & 7)) << 4);
      *(bf16x8*)(A0 + off) = h0;
      *(bf16x8*)(A1 + off) = h1;
    }
    __syncthreads();
#pragma unroll
    for (int ks = 0; ks < 2; ks++) {
      int sl = ks * 4 + (lane >> 4);
      bf16x8 a0[2], a1[2], bfr[4];
#pragma unroll
      for (int mi = 0; mi < 2; mi++) {
        int row = wm * 32 + mi * 16 + (lane & 15);
        int off = row * 128 + ((sl ^ (row & 7)) << 4);
        a0[mi] = *(const bf16x8*)(A0 + off);
        a1[mi] = *(const bf16x8*)(A1 + off);
      }
#pragma unroll
      for (int ni = 0; ni < 4; ni++) {
        int row = wn * 64 + ni * 16 + (lane & 15);
        bfr[ni] = *(const bf16x8*)(Bb + row * 128 + ((sl ^ (row & 7)) << 4));
      }
#pragma unroll
      for (int mi = 0; mi < 2; mi++)
#pragma unroll
        for (int ni = 0; ni < 4; ni++) {
          acc0[mi][ni] = __builtin_amdgcn_mfma_f32_16x16x32_bf16(a0[mi], bfr[ni], acc0[mi][ni], 0, 0, 0);
          acc1[mi][ni] = __builtin_amdgcn_mfma_f32_16x16x32_bf16(a1[mi], bfr[ni], acc1[mi][ni], 0, 0, 0);
        }
    }
    __syncthreads();
  }
#pragma unroll
  for (int mi = 0; mi < 2; mi++) {
    int cob = co0 + wm * 32 + mi * 16 + ((lane >> 4) << 2);
    f32x4 bia0 = *(const f32x4*)(L.b0 + cob);
    f32x4 bia1 = *(const f32x4*)(L.b1 + cob);
#pragma unroll
    for (int ni = 0; ni < 4; ni++) {
      int n = wn * 64 + ni * 16 + (lane & 15);
      int p = p0 + n;
      if (p >= HW) continue;
      u16x4 res = *(const u16x4*)(fTb + (size_t)p * C + cob);
      u16x4 o0, o1;
#pragma unroll
      for (int j = 0; j < 4; j++) {
        float x0 = acc0[mi][ni][j] + bia0[j];
        o0[j] = f2bf(x0 * sigm(x0) + bf2f(res[j]));
        float x1 = acc1[mi][ni][j] + bia1[j];
        o1[j] = f2bf(x1 * sigm(x1));
      }
      size_t off = ((size_t)b * HW + p) * C + cob;
      *(u16x4*)(L.tcT + off) = o0;
      *(u16x4*)(L.trT + off) = o1;
    }
  }
}

// ---------------- conv1g NEW: all-gll staging (A from precomputed gated weights) ----------------
struct C1GLvl {
  const u16 *gwc, *gwr;       // [b][co][ci] bf16 gated weights, level base
  const float *b0, *b1;
  const u16* fT;
  u16 *tcT, *trT;
  int C, HW, ntiles, mblks, bstart;
};
struct C1GArgs { C1GLvl l[3]; const u16* zp; };

__global__ __launch_bounds__(256) void k_conv1g(C1GArgs A) {
  __shared__ char smem[32768];  // A0 8K | A1 8K | B 16K
  int bid = blockIdx.x;
  int li = (bid >= A.l[2].bstart) ? 2 : (bid >= A.l[1].bstart ? 1 : 0);
  const C1GLvl& L = A.l[li];
  int loc = bid - L.bstart;
  int mb = loc % L.mblks;
  int t2 = loc / L.mblks;
  int nt = t2 % L.ntiles;
  int b = t2 / L.ntiles;
  const int C = L.C, HW = L.HW;
  int p0 = nt * 128, co0 = mb * 64;
  int tid = threadIdx.x, lane = tid & 63, w = tid >> 6;
  int wm = w >> 1, wn = w & 1;
  char* A0 = smem;
  char* A1 = smem + 8192;
  char* Bb = smem + 16384;
  const u16* fTb = L.fT + (size_t)b * HW * C;
  const u16* gw0 = L.gwc + (size_t)b * C * C;
  const u16* gw1 = L.gwr + (size_t)b * C * C;
  int sl8 = lane & 7;

  // B staging sources (4 passes of 8 rows per wave)
  const u16* bsrc[4];
  bool bval[4];
#pragma unroll
  for (int i = 0; i < 4; i++) {
    int r = w * 32 + i * 8 + (lane >> 3);
    int p = p0 + r;
    bval[i] = p < HW;
    bsrc[i] = bval[i] ? (fTb + (size_t)p * C + ((sl8 ^ (r & 7)) << 3)) : A.zp;
  }
  // A staging sources (2 passes of 8 rows per wave per branch)
  const u16* a0src[2];
  const u16* a1src[2];
  int adst[2];
#pragma unroll
  for (int i = 0; i < 2; i++) {
    int r = w * 16 + i * 8 + (lane >> 3);
    adst[i] = r;  // row base for this pass (dest uses w*16+i*8)
    a0src[i] = gw0 + (size_t)(co0 + r) * C + ((sl8 ^ (r & 7)) << 3);
    a1src[i] = gw1 + (size_t)(co0 + r) * C + ((sl8 ^ (r & 7)) << 3);
  }

  f32x4 acc0[2][4], acc1[2][4];
#pragma unroll
  for (int mi = 0; mi < 2; mi++)
#pragma unroll
    for (int ni = 0; ni < 4; ni++) { acc0[mi][ni] = (f32x4){0.f,0.f,0.f,0.f}; acc1[mi][ni] = (f32x4){0.f,0.f,0.f,0.f}; }

  const int nchunk = C >> 6;
  for (int c = 0; c < nchunk; c++) {
    int ci0 = c << 6;
#pragma unroll
    for (int i = 0; i < 4; i++) {
      const void* src = bval[i] ? (const void*)(bsrc[i] + ci0) : (const void*)A.zp;
      gll16(src, Bb + (w * 32 + i * 8) * 128);
    }
#pragma unroll
    for (int i = 0; i < 2; i++) {
      gll16(a0src[i] + ci0, A0 + (w * 16 + i * 8) * 128);
      gll16(a1src[i] + ci0, A1 + (w * 16 + i * 8) * 128);
    }
    __syncthreads();
#pragma unroll
    for (int ks = 0; ks < 2; ks++) {
      int sl = ks * 4 + (lane >> 4);
      bf16x8 a0[2], a1[2], bfr[4];
#pragma unroll
      for (int mi = 0; mi < 2; mi++) {
        int row = wm * 32 + mi * 16 + (lane & 15);
        int off = row * 128 + ((sl ^ (row & 7)) << 4);
        a0[mi] = *(const bf16x8*)(A0 + off);
        a1[mi] = *(const bf16x8*)(A1 + off);
      }
#pragma unroll
      for (int ni = 0; ni < 4; ni++) {
        int row = wn * 64 + ni * 16 + (lane & 15);
        bfr[ni] = *(const bf16x8*)(Bb + row * 128 + ((sl ^ (row & 7)) << 4));
      }
#pragma unroll
      for (int mi = 0; mi < 2; mi++)
#pragma unroll
        for (int ni = 0; ni < 4; ni++) {
          acc0[mi][ni] = __builtin_amdgcn_mfma_f32_16x16x32_bf16(a0[mi], bfr[ni], acc0[mi][ni], 0, 0, 0);
          acc1[mi][ni] = __builtin_amdgcn_mfma_f32_16x16x32_bf16(a1[mi], bfr[ni], acc1[mi][ni], 0, 0, 0);
        }
    }
    __syncthreads();
  }
#pragma unroll
  for (int mi = 0; mi < 2; mi++) {
    int cob = co0 + wm * 32 + mi * 16 + ((lane >> 4) << 2);
    f32x4 bia0 = *(const f32x4*)(L.b0 + cob);
    f32x4 bia1 = *(const f32x4*)(L.b1 + cob);
#pragma unroll
    for (int ni = 0; ni < 4; ni++) {
      int n = wn * 64 + ni * 16 + (lane & 15);
      int p = p0 + n;
      if (p >= HW) continue;
      u16x4 res = *(const u16x4*)(fTb + (size_t)p * C + cob);
      u16x4 o0, o1;
#pragma unroll
      for (int j = 0; j < 4; j++) {
        float x0 = acc0[mi][ni][j] + bia0[j];
        o0[j] = f2bf(x0 * sigm(x0) + bf2f(res[j]));
        float x1 = acc1[mi][ni][j] + bia1[j];
        o1[j] = f2bf(x1 * sigm(x1));
      }
      size_t off = ((size_t)b * HW + p) * C + cob;
      *(u16x4*)(L.tcT + off) = o0;
      *(u16x4*)(L.trT + off) = o1;
    }
  }
}

// ---------------- conv3: 3x3 MFMA implicit GEMM (tap-outer) ----------------
struct C3Lvl {
  const u16* inT;
  const float* w;
  const u16* wT;
  const float* bias;
  int C, W, H, HW, ntiles, bstart, pos_off;
};
struct C3Args { C3Lvl l[3]; const u16* zp; float* out; };

template<int MREAL, int EPI, bool WT>
__global__ __launch_bounds__(256) void k_conv3(C3Args A) {
  __shared__ char smem[EPI == 3 ? 34816 : 28672];
  char* Ab = smem;
  char* Bb = smem + 12288;
  int bid = blockIdx.x;
  int li = (bid >= A.l[2].bstart) ? 2 : (bid >= A.l[1].bstart ? 1 : 0);
  const C3Lvl& L = A.l[li];
  int loc = bid - L.bstart;
  int nt = loc % L.ntiles;
  int b = loc / L.ntiles;
  const int C = L.C, W = L.W, H = L.H, HW = L.HW;
  int p0 = nt * 128;
  int tid = threadIdx.x, lane = tid & 63, w = tid >> 6;
  int wm = w >> 1, wn = w & 1;
  int sl8 = lane & 7;
  const u16* inb = L.inT + (size_t)b * HW * C;

  int rr[4], px[4], py[4];
  bool pv[4];
#pragma unroll
  for (int i = 0; i < 4; i++) {
    int r = w * 32 + i * 8 + (lane >> 3);
    rr[i] = r;
    int p = p0 + r;
    pv[i] = p < HW;
    int pp = pv[i] ? p : 0;
    px[i] = pp % W;
    py[i] = pp / W;
  }

  f32x4 acc[3][4];
#pragma unroll
  for (int mi = 0; mi < 3; mi++)
#pragma unroll
    for (int ni = 0; ni < 4; ni++) acc[mi][ni] = (f32x4){0.f,0.f,0.f,0.f};

  const int nchunk = C >> 6;
  for (int t = 0; t < 9; t++) {
    int dy = t / 3 - 1, dx = t - (t / 3) * 3 - 1;
    const u16* bs[4];
    bool bv[4];
#pragma unroll
    for (int i = 0; i < 4; i++) {
      int xx = px[i] + dx, yy = py[i] + dy;
      bool ok = pv[i] && ((unsigned)xx < (unsigned)W) && ((unsigned)yy < (unsigned)H);
      bv[i] = ok;
      int q = p0 + rr[i] + dy * W + dx;
      bs[i] = ok ? (inb + (size_t)q * C + ((sl8 ^ (rr[i] & 7)) << 3)) : A.zp;
    }
    for (int c = 0; c < nchunk; c++) {
      int ci0 = c << 6;
      if (WT) {
        const u16* wl = L.wT;
#pragma unroll
        for (int g = 0; g < 3; g++) {
          int row = w * 24 + g * 8 + (lane >> 3);
          const u16* src = wl + ((size_t)(t * 96 + row)) * C + ci0 + ((sl8 ^ (row & 7)) << 3);
          gll16(src, Ab + (w * 24 + g * 8) * 128);
        }
      } else {
#pragma unroll
        for (int g = 0; g < 3; g++) {
          int u = g * 256 + tid;
          int am = u >> 3, as = u & 7;
          bf16x8 h;
          if (am < MREAL) {
            const float* wp = L.w + ((size_t)am * C + ci0 + as * 8) * 9 + t;
#pragma unroll
            for (int j = 0; j < 8; j++) h[j] = (short)f2bf(wp[j * 9]);
          } else {
#pragma unroll
            for (int j = 0; j < 8; j++) h[j] = 0;
          }
          *(bf16x8*)(Ab + am * 128 + ((as ^ (am & 7)) << 4)) = h;
        }
      }
#pragma unroll
      for (int i = 0; i < 4; i++) {
        const void* src = bv[i] ? (const void*)(bs[i] + ci0) : (const void*)A.zp;
        gll16(src, Bb + (w * 32 + i * 8) * 128);
      }
      __syncthreads();
#pragma unroll
      for (int ks = 0; ks < 2; ks++) {
        int sl = ks * 4 + (lane >> 4);
        bf16x8 af[3], bfr[4];
#pragma unroll
        for (int mi = 0; mi < 3; mi++) {
          int row = wm * 48 + mi * 16 + (lane & 15);
          af[mi] = *(const bf16x8*)(Ab + row * 128 + ((sl ^ (row & 7)) << 4));
        }
#pragma unroll
        for (int ni = 0; ni < 4; ni++) {
          int row = wn * 64 + ni * 16 + (lane & 15);
          bfr[ni] = *(const bf16x8*)(Bb + row * 128 + ((sl ^ (row & 7)) << 4));
        }
#pragma unroll
        for (int mi = 0; mi < 3; mi++)
#pragma unroll
          for (int ni = 0; ni < 4; ni++)
            acc[mi][ni] = __builtin_amdgcn_mfma_f32_16x16x32_bf16(af[mi], bfr[ni], acc[mi][ni], 0, 0, 0);
      }
      __syncthreads();
    }
  }

  if (EPI == 2) {
#pragma unroll
    for (int mi = 0; mi < 3; mi++) {
      int cob = wm * 48 + mi * 16 + ((lane >> 4) << 2);
      if (cob >= 80) continue;
      f32x4 bia = *(const f32x4*)(L.bias + cob);
#pragma unroll
      for (int ni = 0; ni < 4; ni++) {
        int n = wn * 64 + ni * 16 + (lane & 15);
        int p = p0 + n;
        if (p >= HW) continue;
#pragma unroll
        for (int j = 0; j < 4; j++) {
          A.out[(size_t)(b * 80 + cob + j) * 8400 + L.pos_off + p] = sigm(acc[mi][ni][j] + bia[j]);
        }
      }
    }
  } else {
    float* P = (float*)smem;
#pragma unroll
    for (int mi = 0; mi < 3; mi++) {
      int cob = wm * 48 + mi * 16 + ((lane >> 4) << 2);
      if (cob < 68) {
        f32x4 bia = *(const f32x4*)(L.bias + cob);
#pragma unroll
        for (int ni = 0; ni < 4; ni++) {
          int n = wn * 64 + ni * 16 + (lane & 15);
          f32x4 v = acc[mi][ni];
#pragma unroll
          for (int j = 0; j < 4; j++) v[j] += bia[j];
          *(f32x4*)(P + n * 68 + cob) = v;
        }
      }
    }
    __syncthreads();
    int n = tid >> 1, g2 = tid & 1;
    int p = p0 + n;
    if (p < HW) {
      float d[2];
#pragma unroll
      for (int gg = 0; gg < 2; gg++) {
        const float* row = P + n * 68 + (g2 * 2 + gg) * 17;
        float mx = row[0];
#pragma unroll
        for (int k = 1; k < 17; k++) mx = fmaxf(mx, row[k]);
        float sum = 0.f, dot = 0.f;
#pragma unroll
        for (int k = 0; k < 17; k++) {
          float e = __expf(row[k] - mx);
          sum += e;
          dot += (float)k * e;
        }
        d[gg] = dot / sum;
      }
      float2 dv = make_float2(d[0], d[1]);
      *(float2*)(A.out + RO + ((size_t)b * 8400 + L.pos_off + p) * 4 + g2 * 2) = dv;
    }
  }
}

// ---------------- host ----------------
extern "C" void kernel_launch(void* const* d_in, const int* in_sizes, int n_in,
                              void* d_out, int out_size, void* d_ws, size_t ws_size,
                              hipStream_t stream) {
  static const int Cs[3] = {768, 384, 192};
  static const int HWs[3] = {400, 1600, 6400};
  static const int Ws[3] = {20, 40, 80};
  static const int POs[3] = {0, 400, 2000};
  static const long TOFF[3] = {0, 4915200, 14745600};
  static const long WTOFF[3] = {0, 663552, 995328};
  static const long GOFF[3] = {0, 9437184, 11796480};   // per-branch gw offsets (elems)
  static const int NT[3] = {4, 13, 50};
  static const int MB[3] = {12, 6, 3};

  char* wsb = (char*)d_ws;
  u16* zp = (u16*)wsb;
  float* avg = (float*)(wsb + 256);
  float* gc = avg + 3 * BSZ * 768;
  float* gr = gc + 3 * BSZ * 768;
  u16* tcT = (u16*)(gr + 3 * BSZ * 768);
  u16* trT = tcT + 34406400;
  u16* wTc = trT + 34406400;
  u16* wTr = wTc + 1161216;
  u16* featT = wTr + 1161216;
  u16* gwc = featT + 34406400;
  u16* gwr = gwc + 12386304;
  const size_t NEED_WT = 142713088ull;
  const size_t NEED_NEW = 211525888ull;
  const size_t NEED_GW = 261071104ull;
  bool useWT = ws_size >= NEED_WT;
  bool useNEW = ws_size >= NEED_NEW;
  bool useGW = ws_size >= NEED_GW;

  hipMemsetAsync(zp, 0, 256, stream);

  SmallArgs SA;
  for (int l = 0; l < 3; l++) {
    const float* const* p = (const float* const*)(d_in + l * 13);
    SA.feat[l] = p[0];
    SA.cfw[l] = p[1]; SA.cfb[l] = p[2];
    SA.rfw[l] = p[3]; SA.rfb[l] = p[4];
  }
  SA.avg = avg; SA.gc = gc; SA.gr = gr;

  if (useWT) {
    hipMemsetAsync(wTc, 0, 2 * 1161216ull * 2, stream);
    for (int l = 0; l < 3; l++) {
      const float* pcw = (const float*)d_in[l * 13 + 9];
      const float* prw = (const float*)d_in[l * 13 + 11];
      hipLaunchKernelGGL(k_wprep, dim3(80 * Cs[l] / 256), dim3(256), 0, stream, pcw, wTc + WTOFF[l], Cs[l]);
      hipLaunchKernelGGL(k_wprep, dim3(68 * Cs[l] / 256), dim3(256), 0, stream, prw, wTr + WTOFF[l], Cs[l]);
    }
  }

  if (useNEW) {
    PFArgs PF;
    for (int l = 0; l < 3; l++) {
      PF.feat[l] = SA.feat[l];
      PF.fT[l] = featT + TOFF[l];
    }
    int ps1 = BSZ * 7, ps2 = ps1 + BSZ * 25, ptot = ps2 + BSZ * 100;
    hipLaunchKernelGGL(k_prepF2, dim3(ptot), dim3(256), 0, stream, PF, ps1, ps2);
  }

  int s1 = BSZ * 768, s2 = s1 + BSZ * 384, tot = s2 + BSZ * 192;
  hipLaunchKernelGGL(k_avg, dim3(tot), dim3(256), 0, stream, SA, s1, s2);
  hipLaunchKernelGGL(k_gate, dim3(tot), dim3(256), 0, stream, SA, s1, s2);

  if (useGW) {
    GWArgs GW;
    for (int l = 0; l < 3; l++) {
      const float* const* p = (const float* const*)(d_in + l * 13);
      GW.w0[l] = p[5];
      GW.w1[l] = p[7];
      GW.goff[l] = GOFF[l];
    }
    GW.gc = gc; GW.gr = gr;
    GW.gwc = gwc; GW.gwr = gwr;
    int g1 = BSZ * 288, g2 = g1 + BSZ * 72, gtot = g2 + BSZ * 18;
    hipLaunchKernelGGL(k_wgate, dim3(gtot), dim3(256), 0, stream, GW, g1, g2);
  }

  int bstart = 0;
  if (useGW) {
    C1GArgs C1;
    for (int l = 0; l < 3; l++) {
      const float* const* p = (const float* const*)(d_in + l * 13);
      C1GLvl& L = C1.l[l];
      L.gwc = gwc + GOFF[l];
      L.gwr = gwr + GOFF[l];
      L.b0 = p[6]; L.b1 = p[8];
      L.fT = featT + TOFF[l];
      L.tcT = tcT + TOFF[l];
      L.trT = trT + TOFF[l];
      L.C = Cs[l]; L.HW = HWs[l]; L.ntiles = NT[l]; L.mblks = MB[l];
      L.bstart = bstart;
      bstart += BSZ * NT[l] * MB[l];
    }
    C1.zp = zp;
    hipLaunchKernelGGL(k_conv1g, dim3(bstart), dim3(256), 0, stream, C1);
  } else if (useNEW) {
    C1NArgs C1;
    for (int l = 0; l < 3; l++) {
      const float* const* p = (const float* const*)(d_in + l * 13);
      C1NLvl& L = C1.l[l];
      L.w0 = p[5]; L.b0 = p[6];
      L.w1 = p[7]; L.b1 = p[8];
      L.gc = gc + l * BSZ * 768;
      L.gr = gr + l * BSZ * 768;
      L.fT = featT + TOFF[l];
      L.tcT = tcT + TOFF[l];
      L.trT = trT + TOFF[l];
      L.C = Cs[l]; L.HW = HWs[l]; L.ntiles = NT[l]; L.mblks = MB[l];
      L.bstart = bstart;
      bstart += BSZ * NT[l] * MB[l];
    }
    C1.zp = zp;
    hipLaunchKernelGGL(k_conv1n, dim3(bstart), dim3(256), 0, stream, C1);
  } else {
    C1Args C1;
    for (int l = 0; l < 3; l++) {
      const float* const* p = (const float* const*)(d_in + l * 13);
      C1Lvl& L = C1.l[l];
      L.feat = p[0];
      L.w0 = p[5]; L.b0 = p[6];
      L.w1 = p[7]; L.b1 = p[8];
      L.gc = gc + l * BSZ * 768;
      L.gr = gr + l * BSZ * 768;
      L.tcT = tcT + TOFF[l];
      L.trT = trT + TOFF[l];
      L.C = Cs[l]; L.HW = HWs[l]; L.ntiles = NT[l]; L.mblks = MB[l];
      L.bstart = bstart;
      bstart += BSZ * NT[l] * MB[l];
    }
    hipLaunchKernelGGL(k_conv1, dim3(bstart), dim3(256), 0, stream, C1);
  }

  C3Args C3c, C3r;
  int bs3 = 0;
  for (int l = 0; l < 3; l++) {
    const float* const* p = (const float* const*)(d_in + l * 13);
    C3Lvl Lc, Lr;
    Lc.inT = tcT + TOFF[l]; Lc.w = p[9]; Lc.wT = wTc + WTOFF[l]; Lc.bias = p[10];
    Lr.inT = trT + TOFF[l]; Lr.w = p[11]; Lr.wT = wTr + WTOFF[l]; Lr.bias = p[12];
    Lc.C = Lr.C = Cs[l]; Lc.W = Lr.W = Ws[l]; Lc.H = Lr.H = Ws[l]; Lc.HW = Lr.HW = HWs[l];
    Lc.ntiles = Lr.ntiles = NT[l];
    Lc.bstart = Lr.bstart = bs3;
    Lc.pos_off = Lr.pos_off = POs[l];
    C3c.l[l] = Lc; C3r.l[l] = Lr;
    bs3 += BSZ * NT[l];
  }
  C3c.zp = zp; C3c.out = (float*)d_out;
  C3r.zp = zp; C3r.out = (float*)d_out;

  if (useWT) {
    hipLaunchKernelGGL((k_conv3<80, 2, true>), dim3(bs3), dim3(256), 0, stream, C3c);
    hipLaunchKernelGGL((k_conv3<68, 3, true>), dim3(bs3), dim3(256), 0, stream, C3r);
  } else {
    hipLaunchKernelGGL((k_conv3<80, 2, false>), dim3(bs3), dim3(256), 0, stream, C3c);
    hipLaunchKernelGGL((k_conv3<68, 3, false>), dim3(bs3), dim3(256), 0, stream, C3r);
  }

  hipLaunchKernelGGL(k_anchor, dim3(33), dim3(256), 0, stream, (float*)d_out);
}